// Round 6
// baseline (525.028 us; speedup 1.0000x reference)
//
#include <hip/hip_runtime.h>
#include <math.h>

#define N_NODES 5000
#define E_EDGES 160000
#define H_HEADS 6
#define D_FEAT  64
#define IN_FEAT 131
#define HD      384          // H*D
#define NC4     (N_NODES/4)  // 1250
#define AGG_CAP 1024
#define MPAD    5024         // 157 row-blocks * 32 rows (zero-padded tail)
#define KP0     160          // layer0 K=131 padded to multiple of 32

typedef float vf4   __attribute__((ext_vector_type(4)));
typedef float f32x4 __attribute__((ext_vector_type(4)));
typedef _Float16 h16;
typedef _Float16 half8 __attribute__((ext_vector_type(8)));

// monotone float<->uint encode so atomicMax(uint) == float max (all finite values)
__device__ __forceinline__ unsigned f2ord(float x) {
    unsigned b = __float_as_uint(x);
    return (b & 0x80000000u) ? ~b : (b | 0x80000000u);
}
__device__ __forceinline__ float ord2f(unsigned o) {
    return (o & 0x80000000u) ? __uint_as_float(o & 0x7fffffffu)
                             : __uint_as_float(~o);
}

// ---------------- CSR build ----------------
__global__ void k_count(const int* __restrict__ dst, int* __restrict__ deg) {
    int e = blockIdx.x * blockDim.x + threadIdx.x;
    if (e < E_EDGES) atomicAdd(&deg[dst[e]], 1);
}

__global__ void k_scan(int* __restrict__ deg, int* __restrict__ row_ptr) {
    __shared__ int part[1024];
    const int T = 1024;
    int t = threadIdx.x;
    const int per = (N_NODES + T - 1) / T;   // 5
    int start = t * per;
    int s = 0;
    for (int i = 0; i < per; i++) {
        int idx = start + i;
        if (idx < N_NODES) s += deg[idx];
    }
    part[t] = s;
    __syncthreads();
    for (int off = 1; off < T; off <<= 1) {
        int v = (t >= off) ? part[t - off] : 0;
        __syncthreads();
        part[t] += v;
        __syncthreads();
    }
    int excl = (t == 0) ? 0 : part[t - 1];
    for (int i = 0; i < per; i++) {
        int idx = start + i;
        if (idx < N_NODES) {
            row_ptr[idx] = excl;
            excl += deg[idx];
            deg[idx] = 0;     // reset as fill cursor
        }
    }
    if (t == T - 1) row_ptr[N_NODES] = part[T - 1];
}

__global__ void k_fill(const int* __restrict__ src, const int* __restrict__ dst,
                       const int* __restrict__ row_ptr,
                       int* __restrict__ cursor, int* __restrict__ csrc) {
    int e = blockIdx.x * blockDim.x + threadIdx.x;
    if (e < E_EDGES) {
        int d = dst[e];
        int p = atomicAdd(&cursor[d], 1);
        csrc[row_ptr[d] + p] = src[e];
    }
}

// ---------------- fp32 -> f16 hi/lo split: layer0 A ----------------
__global__ void k_cvt_a0(const float* __restrict__ A, h16* __restrict__ hi,
                         h16* __restrict__ lo) {
    int idx = blockIdx.x * blockDim.x + threadIdx.x;
    if (idx >= MPAD * KP0) return;
    int r = idx / KP0, k = idx - r * KP0;
    float v = (r < N_NODES && k < IN_FEAT) ? A[r * IN_FEAT + k] : 0.f;
    h16 h = (h16)v;
    hi[idx] = h;
    lo[idx] = (h16)(v - (float)h);
}

// ---------------- all-layer W transpose+split, coalesced via LDS tile ----------
struct CvtArgs {
    const float *W0, *W1, *W2, *W3;
    h16 *hi0, *lo0, *hi1, *lo1, *hi2, *lo2, *hi3, *lo3;
};
__global__ void k_cvt_wT(CvtArgs a) {
    __shared__ float tile[32][33];
    int z = blockIdx.z;
    const float* W = z == 0 ? a.W0 : z == 1 ? a.W1 : z == 2 ? a.W2 : a.W3;
    h16* hi = z == 0 ? a.hi0 : z == 1 ? a.hi1 : z == 2 ? a.hi2 : a.hi3;
    h16* lo = z == 0 ? a.lo0 : z == 1 ? a.lo1 : z == 2 ? a.lo2 : a.lo3;
    int K  = (z == 0) ? IN_FEAT : HD;
    int KP = (z == 0) ? KP0 : HD;
    int k0 = blockIdx.y * 32;
    if (k0 >= KP) return;
    int n0 = blockIdx.x * 32;
    int tx = threadIdx.x & 31, ty = threadIdx.x >> 5;   // 32x8
#pragma unroll
    for (int j = 0; j < 4; j++) {
        int kk = ty + j * 8;
        int gk = k0 + kk;
        tile[kk][tx] = (gk < K) ? W[(size_t)gk * HD + n0 + tx] : 0.f;
    }
    __syncthreads();
#pragma unroll
    for (int j = 0; j < 4; j++) {
        int nn = ty + j * 8;
        float v = tile[tx][nn];
        h16 hh = (h16)v;
        size_t o = (size_t)(n0 + nn) * KP + k0 + tx;
        hi[o] = hh;
        lo[o] = (h16)(v - (float)hh);
    }
}

// ---------------- MFMA GEMM (f16 hi/lo x3 ~= fp32), reg double-buffer ---------
// One wave/block, tile 32 rows x 64 cols (head h). Explicit 2-deep prefetch:
// K-step t+1's 12 x 16B loads issue before step t's 24 MFMAs -> L2 latency
// hidden at ~1 wave/SIMD (grid-limited occupancy). Static reg names (no runtime
// indexing -> no scratch). Epilogue: fused el/er + per-head el-max (ord atomicMax).
struct KRegs {
    half8 a0h, a0l, a1h, a1l;
    half8 bh0, bh1, bh2, bh3;
    half8 bl0, bl1, bl2, bl3;
};
#define MF(A, B, C) C = __builtin_amdgcn_mfma_f32_16x16x32_f16(A, B, C, 0, 0, 0)

__device__ __forceinline__ void load_step(KRegs& r,
        const h16* a0h, const h16* a0l, const h16* a1h, const h16* a1l,
        const h16* bh, const h16* bl, int KP, int k0) {
    r.a0h = *(const half8*)(a0h + k0);
    r.a0l = *(const half8*)(a0l + k0);
    r.a1h = *(const half8*)(a1h + k0);
    r.a1l = *(const half8*)(a1l + k0);
    r.bh0 = *(const half8*)(bh + k0);
    r.bh1 = *(const half8*)(bh + (size_t)16 * KP + k0);
    r.bh2 = *(const half8*)(bh + (size_t)32 * KP + k0);
    r.bh3 = *(const half8*)(bh + (size_t)48 * KP + k0);
    r.bl0 = *(const half8*)(bl + k0);
    r.bl1 = *(const half8*)(bl + (size_t)16 * KP + k0);
    r.bl2 = *(const half8*)(bl + (size_t)32 * KP + k0);
    r.bl3 = *(const half8*)(bl + (size_t)48 * KP + k0);
}
__device__ __forceinline__ void mfma_step(const KRegs& r, f32x4 acc[2][4]) {
    MF(r.a0h, r.bh0, acc[0][0]); MF(r.a0l, r.bh0, acc[0][0]); MF(r.a0h, r.bl0, acc[0][0]);
    MF(r.a1h, r.bh0, acc[1][0]); MF(r.a1l, r.bh0, acc[1][0]); MF(r.a1h, r.bl0, acc[1][0]);
    MF(r.a0h, r.bh1, acc[0][1]); MF(r.a0l, r.bh1, acc[0][1]); MF(r.a0h, r.bl1, acc[0][1]);
    MF(r.a1h, r.bh1, acc[1][1]); MF(r.a1l, r.bh1, acc[1][1]); MF(r.a1h, r.bl1, acc[1][1]);
    MF(r.a0h, r.bh2, acc[0][2]); MF(r.a0l, r.bh2, acc[0][2]); MF(r.a0h, r.bl2, acc[0][2]);
    MF(r.a1h, r.bh2, acc[1][2]); MF(r.a1l, r.bh2, acc[1][2]); MF(r.a1h, r.bl2, acc[1][2]);
    MF(r.a0h, r.bh3, acc[0][3]); MF(r.a0l, r.bh3, acc[0][3]); MF(r.a0h, r.bl3, acc[0][3]);
    MF(r.a1h, r.bh3, acc[1][3]); MF(r.a1l, r.bh3, acc[1][3]); MF(r.a1h, r.bl3, acc[1][3]);
}

__global__ __launch_bounds__(64, 2) void k_gemm_mfma(
        const h16* __restrict__ Ahi, const h16* __restrict__ Alo,
        const h16* __restrict__ Wthi, const h16* __restrict__ Wtlo,
        const float* __restrict__ al, const float* __restrict__ ar,
        float* __restrict__ C, float* __restrict__ el, float* __restrict__ er,
        unsigned* __restrict__ maxel, int KP) {
    int lane = threadIdx.x;          // 0..63
    int h = blockIdx.x;              // head (0..5)
    int rb = blockIdx.y * 32;
    int cb = h * 64;
    int l15 = lane & 15, lg = lane >> 4;
    f32x4 acc[2][4] = {};

    const h16* a0h = Ahi + (size_t)(rb + l15) * KP + (lg << 3);
    const h16* a0l = Alo + (size_t)(rb + l15) * KP + (lg << 3);
    const h16* a1h = a0h + (size_t)16 * KP;
    const h16* a1l = a0l + (size_t)16 * KP;
    const h16* bh = Wthi + (size_t)(cb + l15) * KP + (lg << 3);
    const h16* bl = Wtlo + (size_t)(cb + l15) * KP + (lg << 3);

    KRegs r0, r1;
    load_step(r0, a0h, a0l, a1h, a1l, bh, bl, KP, 0);
    const int T = KP >> 5;
    int t = 0;
    for (; t + 2 <= T; t += 2) {
        load_step(r1, a0h, a0l, a1h, a1l, bh, bl, KP, (t + 1) << 5);
        mfma_step(r0, acc);
        if (t + 2 < T)
            load_step(r0, a0h, a0l, a1h, a1l, bh, bl, KP, (t + 2) << 5);
        mfma_step(r1, acc);
    }
    if (t < T) mfma_step(r0, acc);   // odd-T tail (already loaded in r0)

    // epilogue: C store + fused el/er + per-head el max
    float alv[4], arv[4];
#pragma unroll
    for (int q = 0; q < 4; q++) {
        alv[q] = al[h * D_FEAT + q * 16 + l15];
        arv[q] = ar[h * D_FEAT + q * 16 + l15];
    }
    float elmax = -1e30f;
#pragma unroll
    for (int m = 0; m < 2; m++) {
#pragma unroll
        for (int r = 0; r < 4; r++) {
            int grow = rb + m * 16 + lg * 4 + r;
            float sl = 0.f, sr = 0.f;
#pragma unroll
            for (int q = 0; q < 4; q++) {
                float v = acc[m][q][r];
                if (grow < N_NODES) C[(size_t)grow * HD + cb + q * 16 + l15] = v;
                sl += v * alv[q];
                sr += v * arv[q];
            }
#pragma unroll
            for (int off = 1; off < 16; off <<= 1) {
                sl += __shfl_xor(sl, off);
                sr += __shfl_xor(sr, off);
            }
            elmax = fmaxf(elmax, sl);   // pad rows give el=0: only loosens bound
            if (l15 == 0 && grow < N_NODES) {
                el[grow * H_HEADS + h] = sl;
                er[grow * H_HEADS + h] = sr;
            }
        }
    }
    elmax = fmaxf(elmax, __shfl_xor(elmax, 16));
    elmax = fmaxf(elmax, __shfl_xor(elmax, 32));
    if (lane == 0) atomicMax(&maxel[h], f2ord(elmax));
}

// ---------------- single-pass softmax-aggregate ----------------
// M = lrelu(max_n el[n,h] + er_node) >= every edge score (lrelu monotone), so
// w = exp(x - M) in (0,1] is stable WITHOUT knowing the local max: score+exp+
// gather collapse to ONE pass, no s_x LDS, no extra barriers. ssum is computed
// redundantly (identical) in all 64 lanes -> no reduction needed. Last layer
// fuses head-mean + pw dots (k_embed eliminated).
__global__ __launch_bounds__(384) void k_agg(
        const float* __restrict__ f, const float* __restrict__ el,
        const float* __restrict__ er, const float* __restrict__ bias,
        const int* __restrict__ row_ptr, const int* __restrict__ csrc,
        const unsigned* __restrict__ maxel,
        h16* __restrict__ nhi, h16* __restrict__ nlo,
        const float* __restrict__ pw,
        float* __restrict__ s1g, float* __restrict__ s2g, int last) {
    __shared__ int   s_src[AGG_CAP];
    __shared__ float s_o[H_HEADS][D_FEAT];
    int node = blockIdx.x;
    int t = threadIdx.x;
    int h = t >> 6, lane = t & 63;
    int r0 = row_ptr[node], deg = row_ptr[node + 1] - r0;
    int dcap = deg < AGG_CAP ? deg : AGG_CAP;
    float er_h = er[node * H_HEADS + h];
    float M = ord2f(maxel[h]) + er_h;
    M = M >= 0.f ? M : 0.2f * M;

    for (int i = t; i < dcap; i += 384) s_src[i] = csrc[r0 + i];
    __syncthreads();

    const float* fh = f + h * D_FEAT + lane;
    float acc = 0.f, ssum = 0.f;
    int i = 0;
    int lim = dcap & ~3;
    for (; i < lim; i += 4) {           // 8 loads in flight (4 el bcast + 4 f)
        int sA = s_src[i + 0], sB = s_src[i + 1];
        int sC = s_src[i + 2], sD = s_src[i + 3];
        float eA = el[sA * H_HEADS + h], eB = el[sB * H_HEADS + h];
        float eC = el[sC * H_HEADS + h], eD = el[sD * H_HEADS + h];
        float gA = fh[(size_t)sA * HD], gB = fh[(size_t)sB * HD];
        float gC = fh[(size_t)sC * HD], gD = fh[(size_t)sD * HD];
        float x;
        x = eA + er_h; x = x >= 0.f ? x : 0.2f * x; float wA = __expf(x - M);
        x = eB + er_h; x = x >= 0.f ? x : 0.2f * x; float wB = __expf(x - M);
        x = eC + er_h; x = x >= 0.f ? x : 0.2f * x; float wC = __expf(x - M);
        x = eD + er_h; x = x >= 0.f ? x : 0.2f * x; float wD = __expf(x - M);
        acc += wA * gA; acc += wB * gB; acc += wC * gC; acc += wD * gD;
        ssum += wA + wB + wC + wD;
    }
    for (; i < dcap; i++) {
        int s = s_src[i];
        float e = el[s * H_HEADS + h];
        float g = fh[(size_t)s * HD];
        float x = e + er_h; x = x >= 0.f ? x : 0.2f * x;
        float w = __expf(x - M);
        acc += w * g; ssum += w;
    }
    for (int i2 = AGG_CAP; i2 < deg; i2++) {   // rare tail (deg > CAP)
        int s = csrc[r0 + i2];
        float e = el[s * H_HEADS + h];
        float g = fh[(size_t)s * HD];
        float x = e + er_h; x = x >= 0.f ? x : 0.2f * x;
        float w = __expf(x - M);
        acc += w * g; ssum += w;
    }
    float inv = ssum > 0.f ? 1.f / ssum : 0.f;
    float o = acc * inv + bias[h * D_FEAT + lane];

    if (!last) {
        float oa = o > 0.f ? o : (__expf(o) - 1.f);    // ELU (layers 0-2)
        int oi = node * HD + h * D_FEAT + lane;
        h16 oh = (h16)oa;                              // next layer A operand
        nhi[oi] = oh;
        nlo[oi] = (h16)(oa - (float)oh);
    } else {                                           // fused head-mean + pw dots
        s_o[h][lane] = o;
        __syncthreads();
        if (t < 64) {
            float s = 0.f;
#pragma unroll
            for (int hh = 0; hh < H_HEADS; hh++) s += s_o[hh][t];
            s *= (1.f / 6.f);
            float p1 = s * pw[t];
            float p2 = s * pw[D_FEAT + t];
            for (int off = 32; off; off >>= 1) {
                p1 += __shfl_down(p1, off);
                p2 += __shfl_down(p2, off);
            }
            if (t == 0) { s1g[node] = p1; s2g[node] = p2; }
        }
    }
}

// fast, branchless, numerically-stable tanh
__device__ __forceinline__ float fast_tanh(float z) {
    float t = __expf(-2.f * fabsf(z));
    float r = (1.f - t) / (1.f + t);
    return copysignf(r, z);
}

// ---------------- pairwise tanh output ----------------
__global__ void k_pair(const vf4* __restrict__ dis, const float* __restrict__ s1,
                       const float* __restrict__ s2, const float* __restrict__ pw,
                       const float* __restrict__ pb, vf4* __restrict__ out) {
    const int total = N_NODES * NC4;
    float w = pw[2 * D_FEAT];
    float b = pb[0];
    for (int idx = blockIdx.x * blockDim.x + threadIdx.x; idx < total;
         idx += gridDim.x * blockDim.x) {
        int i = idx / NC4;
        int j4 = idx - i * NC4;
        vf4 dv = __builtin_nontemporal_load(&dis[idx]);
        float base = s2[i] + b;
        int j = j4 * 4;
        vf4 o;
        o.x = fast_tanh(base + s1[j + 0] + dv.x * w);
        o.y = fast_tanh(base + s1[j + 1] + dv.y * w);
        o.z = fast_tanh(base + s1[j + 2] + dv.z * w);
        o.w = fast_tanh(base + s1[j + 3] + dv.w * w);
        __builtin_nontemporal_store(o, &out[idx]);
    }
}

extern "C" void kernel_launch(void* const* d_in, const int* in_sizes, int n_in,
                              void* d_out, int out_size, void* d_ws, size_t ws_size,
                              hipStream_t stream) {
    const float* nfeats = (const float*)d_in[0];
    const float* dis    = (const float*)d_in[1];
    const int*   src    = (const int*)d_in[2];
    const int*   dst    = (const int*)d_in[3];
    const float* w[4]  = {(const float*)d_in[4],  (const float*)d_in[8],
                          (const float*)d_in[12], (const float*)d_in[16]};
    const float* al[4] = {(const float*)d_in[5],  (const float*)d_in[9],
                          (const float*)d_in[13], (const float*)d_in[17]};
    const float* ar[4] = {(const float*)d_in[6],  (const float*)d_in[10],
                          (const float*)d_in[14], (const float*)d_in[18]};
    const float* bs[4] = {(const float*)d_in[7],  (const float*)d_in[11],
                          (const float*)d_in[15], (const float*)d_in[19]};
    const float* pw = (const float*)d_in[20];
    const float* pb = (const float*)d_in[21];
    float* out = (float*)d_out;

    // workspace layout
    float* f     = (float*)d_ws;                // N*HD (gemm output, agg input)
    float* el    = f + (size_t)N_NODES * HD;    // N*H
    float* er    = el + N_NODES * H_HEADS;      // N*H
    float* s1    = er + N_NODES * H_HEADS;      // N
    float* s2    = s1 + N_NODES;                // N
    int* row_ptr = (int*)(s2 + N_NODES);        // N+1
    int* cursor  = row_ptr + (N_NODES + 1);     // N
    int* csrc    = cursor + N_NODES;            // E
    unsigned* maxel = (unsigned*)(csrc + E_EDGES);  // 4 layers x 8 slots
    uintptr_t p = (uintptr_t)(maxel + 32);
    p = (p + 15) & ~(uintptr_t)15;
    h16* A0hi = (h16*)p;                        // MPAD*KP0
    h16* A0lo = A0hi + (size_t)MPAD * KP0;
    h16* Athi = A0lo + (size_t)MPAD * KP0;      // MPAD*HD (layers 1-3 input)
    h16* Atlo = Athi + (size_t)MPAD * HD;
    h16* Wt0hi = Atlo + (size_t)MPAD * HD;      // 384*KP0
    h16* Wt0lo = Wt0hi + (size_t)HD * KP0;
    h16* Wt1hi = Wt0lo + (size_t)HD * KP0;      // 384*384 x6
    h16* Wt1lo = Wt1hi + (size_t)HD * HD;
    h16* Wt2hi = Wt1lo + (size_t)HD * HD;
    h16* Wt2lo = Wt2hi + (size_t)HD * HD;
    h16* Wt3hi = Wt2lo + (size_t)HD * HD;
    h16* Wt3lo = Wt3hi + (size_t)HD * HD;

    // CSR build (dst-indexed)
    (void)hipMemsetAsync(cursor, 0, N_NODES * sizeof(int), stream);
    (void)hipMemsetAsync(maxel, 0, 32 * sizeof(unsigned), stream);  // ord-min
    k_count<<<(E_EDGES + 255) / 256, 256, 0, stream>>>(dst, cursor);
    k_scan<<<1, 1024, 0, stream>>>(cursor, row_ptr);
    k_fill<<<(E_EDGES + 255) / 256, 256, 0, stream>>>(src, dst, row_ptr, cursor, csrc);

    // zero padded tail rows of layer1-3 A buffers (agg writes only <N rows)
    (void)hipMemsetAsync(Athi + (size_t)N_NODES * HD, 0,
                         (size_t)(MPAD - N_NODES) * HD * sizeof(h16), stream);
    (void)hipMemsetAsync(Atlo + (size_t)N_NODES * HD, 0,
                         (size_t)(MPAD - N_NODES) * HD * sizeof(h16), stream);

    // input conversions (one launch for all 4 W's; coalesced LDS transpose)
    k_cvt_a0<<<(MPAD * KP0 + 255) / 256, 256, 0, stream>>>(nfeats, A0hi, A0lo);
    CvtArgs ca = {w[0], w[1], w[2], w[3],
                  Wt0hi, Wt0lo, Wt1hi, Wt1lo, Wt2hi, Wt2lo, Wt3hi, Wt3lo};
    k_cvt_wT<<<dim3(HD / 32, HD / 32, 4), 256, 0, stream>>>(ca);

    dim3 gg(H_HEADS, (N_NODES + 31) / 32);      // (6, 157)
    const h16* Whi[4] = {Wt0hi, Wt1hi, Wt2hi, Wt3hi};
    const h16* Wlo[4] = {Wt0lo, Wt1lo, Wt2lo, Wt3lo};
    for (int l = 0; l < 4; l++) {
        const h16* Ahi = (l == 0) ? A0hi : Athi;
        const h16* Alo = (l == 0) ? A0lo : Atlo;
        int KP = (l == 0) ? KP0 : HD;
        k_gemm_mfma<<<gg, 64, 0, stream>>>(Ahi, Alo, Whi[l], Wlo[l], al[l], ar[l],
                                           f, el, er, maxel + l * 8, KP);
        int last = (l == 3);
        k_agg<<<N_NODES, 384, 0, stream>>>(f, el, er, bs[l], row_ptr, csrc,
                                           maxel + l * 8,
                                           last ? (h16*)nullptr : Athi,
                                           last ? (h16*)nullptr : Atlo,
                                           pw, s1, s2, last);
    }
    k_pair<<<4096, 256, 0, stream>>>((const vf4*)dis, s1, s2, pw, pb, (vf4*)out);
}